// Round 1
// baseline (149.483 us; speedup 1.0000x reference)
//
#include <hip/hip_runtime.h>

#define NEARV   0.2f
#define LOWPASSV 0.3f

constexpr int HH = 80, WW = 80;
constexpr int CFE = 32;          // feature channels
constexpr int GSTRIDE = 40;      // floats per gaussian record (8 hdr + 32 feat)
constexpr int CHUNK = 64;        // gaussians staged per LDS chunk

typedef unsigned long long u64;
typedef unsigned int u32;

// ---------------- Kernel A: per-camera stable depth sort ----------------
// One block per camera. Build 64-bit keys (tz_bits<<32)|index for VALID
// gaussians only (invalid contribute exactly 0 in the reference), stable
// compaction via chunked prefix-sum, then in-LDS bitonic sort. Key layout
// reproduces JAX stable argsort tie-breaking exactly.
__global__ __launch_bounds__(1024) void sort_kernel(
    const float* __restrict__ pc_xyz, const float* __restrict__ cam_rot,
    const float* __restrict__ cam_trans, int N,
    int* __restrict__ counts, int* __restrict__ order)
{
  __shared__ u64 skey[8192];     // 64 KB
  const int cam = blockIdx.x;
  const int tid = threadIdx.x;
  const float R20 = cam_rot[cam*9+6], R21 = cam_rot[cam*9+7], R22 = cam_rot[cam*9+8];
  const float t2  = cam_trans[cam*3+2];

  const int CH  = (N + 1023) >> 10;   // contiguous chunk per thread (stability!)
  const int my0 = tid * CH;
  int cnt = 0;
  for (int i = 0; i < CH; ++i) {
    int n = my0 + i;
    if (n < N) {
      float c2 = R20*pc_xyz[n*3+0] + R21*pc_xyz[n*3+1] + R22*pc_xyz[n*3+2] + t2;
      cnt += (c2 > NEARV) ? 1 : 0;
    }
  }
  skey[tid] = (u64)cnt;
  __syncthreads();
  // inclusive Hillis-Steele scan over 1024 partials
  for (int off = 1; off < 1024; off <<= 1) {
    u64 v = skey[tid];
    u64 a = (tid >= off) ? skey[tid - off] : 0;
    __syncthreads();
    skey[tid] = v + a;
    __syncthreads();
  }
  const int count = (int)skey[1023];
  int base = (int)skey[tid] - cnt;    // exclusive prefix for my chunk
  __syncthreads();                    // all reads of scan results done
  // stable scatter of keys (serial within contiguous chunk)
  for (int i = 0; i < CH; ++i) {
    int n = my0 + i;
    if (n < N) {
      float c2 = R20*pc_xyz[n*3+0] + R21*pc_xyz[n*3+1] + R22*pc_xyz[n*3+2] + t2;
      if (c2 > NEARV) {
        float tz = fmaxf(c2, 1e-6f);
        u64 key = ((u64)__float_as_uint(tz) << 32) | (u32)n;
        skey[base++] = key;
      }
    }
  }
  int M = 1024;
  while (M < count) M <<= 1;          // count <= 8192 (N=6144)
  for (int i = count + tid; i < M; i += 1024) skey[i] = ~0ull;
  __syncthreads();
  // bitonic sort ascending on skey[0..M)
  for (int k = 2; k <= M; k <<= 1) {
    for (int j = k >> 1; j > 0; j >>= 1) {
      for (int i = tid; i < M; i += 1024) {
        int ixj = i ^ j;
        if (ixj > i) {
          u64 a = skey[i], b = skey[ixj];
          bool up = ((i & k) == 0);
          if ((a > b) == up) { skey[i] = b; skey[ixj] = a; }
        }
      }
      __syncthreads();
    }
  }
  for (int kq = tid; kq < count; kq += 1024)
    order[(size_t)cam * N + kq] = (int)(skey[kq] & 0xffffffffu);
  if (tid == 0) counts[cam] = count;
}

// ---------------- Kernel B: project + pack sorted AoS ----------------
__global__ void gather_kernel(
    const float* __restrict__ vox, const float* __restrict__ density,
    const float* __restrict__ cam_rot, const float* __restrict__ cam_trans,
    const float* __restrict__ cam_intr, const float* __restrict__ pc_xyz,
    const float* __restrict__ scales, const float* __restrict__ rots,
    const int* __restrict__ counts, const int* __restrict__ order,
    float* __restrict__ aos, int N, int NC)
{
  const int cam = blockIdx.y;
  const int k = blockIdx.x * blockDim.x + threadIdx.x;
  if (k >= counts[cam]) return;
  const int n = order[(size_t)cam * N + k];
  const int b = cam / NC;
  const float* R = cam_rot + cam*9;
  const float* t = cam_trans + cam*3;
  const float* intr = cam_intr + cam*4;
  float p0 = pc_xyz[n*3+0], p1 = pc_xyz[n*3+1], p2 = pc_xyz[n*3+2];
  float c0 = R[0]*p0 + R[1]*p1 + R[2]*p2 + t[0];
  float c1 = R[3]*p0 + R[4]*p1 + R[5]*p2 + t[1];
  float c2 = R[6]*p0 + R[7]*p1 + R[8]*p2 + t[2];
  float tz = fmaxf(c2, 1e-6f);
  float itz = 1.0f / tz;
  float fx = intr[0], fy = intr[1], cx = intr[2], cy = intr[3];
  float u = fx*c0*itz + cx;
  float v = fy*c1*itz + cy;
  float j00 = fx*itz, j02 = -fx*c0*itz*itz;
  float j11 = fy*itz, j12 = -fy*c1*itz*itz;
  // A = J * Rcw (2x3)
  float A00 = j00*R[0] + j02*R[6];
  float A01 = j00*R[1] + j02*R[7];
  float A02 = j00*R[2] + j02*R[8];
  float A10 = j11*R[3] + j12*R[6];
  float A11 = j11*R[4] + j12*R[7];
  float A12 = j11*R[5] + j12*R[8];
  // Mcov = s * quat_to_rot(q)
  float qw = rots[n*4+0], qx = rots[n*4+1], qy = rots[n*4+2], qz = rots[n*4+3];
  float s = expf(scales[n]);
  float m00 = s*(1.f-2.f*(qy*qy+qz*qz)), m01 = s*(2.f*(qx*qy-qw*qz)), m02 = s*(2.f*(qx*qz+qw*qy));
  float m10 = s*(2.f*(qx*qy+qw*qz)), m11 = s*(1.f-2.f*(qx*qx+qz*qz)), m12 = s*(2.f*(qy*qz-qw*qx));
  float m20 = s*(2.f*(qx*qz-qw*qy)), m21 = s*(2.f*(qy*qz+qw*qx)), m22 = s*(1.f-2.f*(qx*qx+qy*qy));
  float B00 = A00*m00 + A01*m10 + A02*m20;
  float B01 = A00*m01 + A01*m11 + A02*m21;
  float B02 = A00*m02 + A01*m12 + A02*m22;
  float B10 = A10*m00 + A11*m10 + A12*m20;
  float B11 = A10*m01 + A11*m11 + A12*m21;
  float B12 = A10*m02 + A11*m12 + A12*m22;
  float cov00 = B00*B00 + B01*B01 + B02*B02;
  float cov01 = B00*B10 + B01*B11 + B02*B12;
  float cov11 = B10*B10 + B11*B11 + B12*B12;
  float a = cov00 + LOWPASSV, bb = cov01, c = cov11 + LOWPASSV;
  float idet = 1.0f / (a*c - bb*bb);
  float d = density[(size_t)b*N + n];
  float op = fmaxf(d, 0.f) + log1pf(expf(-fabsf(d)));   // softplus, stable
  float* g = aos + ((size_t)cam*N + k) * GSTRIDE;
  g[0]=u; g[1]=v; g[2]=c*idet; g[3]=-bb*idet; g[4]=a*idet; g[5]=op; g[6]=0.f; g[7]=0.f;
  const float4* f4 = (const float4*)(vox + ((size_t)b*N + n)*CFE);
  float4* o4 = (float4*)(g + 8);
  #pragma unroll
  for (int i = 0; i < CFE/4; ++i) o4[i] = f4[i];
}

// ---------------- Kernel C: per-tile front-to-back compositing ----------------
// One 64-lane wave per 16x4 pixel tile. Chunked LDS staging of sorted
// gaussians; per-lane transmittance with wave-uniform early exit.
__global__ __launch_bounds__(64) void render_kernel(
    const float* __restrict__ aos, const int* __restrict__ counts,
    float* __restrict__ out, int N)
{
  __shared__ float sg[CHUNK * GSTRIDE];
  const int cam = blockIdx.y;
  const int tile = blockIdx.x;                 // 5 x 20 tiles of 16x4 px
  const int tx = tile % (WW/16), ty = tile / (WW/16);
  const int lx = threadIdx.x & 15, ly = threadIdx.x >> 4;
  const int px = tx*16 + lx, py = ty*4 + ly;
  const float fpx = (float)px, fpy = (float)py;
  const int count = counts[cam];
  const float* aosCam = aos + (size_t)cam * N * GSTRIDE;

  float acc[CFE];
  #pragma unroll
  for (int i = 0; i < CFE; ++i) acc[i] = 0.f;
  float T = 1.0f;

  for (int k0 = 0; k0 < count; k0 += CHUNK) {
    const int nks = min(CHUNK, count - k0);
    const int nf4 = nks * (GSTRIDE/4);
    const float4* src = (const float4*)(aosCam + (size_t)k0 * GSTRIDE);
    float4* dst = (float4*)sg;
    for (int i = threadIdx.x; i < nf4; i += 64) dst[i] = src[i];
    __syncthreads();
    for (int gi = 0; gi < nks; ++gi) {
      const float* gp = sg + gi * GSTRIDE;     // wave-uniform address: broadcast
      float dx = fpx - gp[0];
      float dy = fpy - gp[1];
      float power = -0.5f*(gp[2]*dx*dx + gp[4]*dy*dy) - gp[3]*dx*dy;
      if (power > -16.0f) {                    // exp(-16)=1.1e-7: negligible
        float gv = expf(fminf(power, 0.0f));
        float alpha = fminf(gp[5]*gv, 0.99f);
        float w = T * alpha;
        T -= w;                                // T *= (1 - alpha)
        if (w > 1e-8f) {
          const float4* f = (const float4*)(gp + 8);
          #pragma unroll
          for (int c8 = 0; c8 < CFE/4; ++c8) {
            float4 fv = f[c8];
            acc[c8*4+0] += w*fv.x; acc[c8*4+1] += w*fv.y;
            acc[c8*4+2] += w*fv.z; acc[c8*4+3] += w*fv.w;
          }
        }
      }
    }
    if (__syncthreads_and(T < 1e-4f)) break;   // all 64 px saturated
  }
  float* ob = out + (((size_t)cam * CFE) * HH + py) * WW + px;
  #pragma unroll
  for (int c = 0; c < CFE; ++c) ob[(size_t)c * HH * WW] = acc[c];
}

extern "C" void kernel_launch(void* const* d_in, const int* in_sizes, int n_in,
                              void* d_out, int out_size, void* d_ws, size_t ws_size,
                              hipStream_t stream) {
  const float* vox       = (const float*)d_in[0];
  const float* density   = (const float*)d_in[1];
  const float* cam_rot   = (const float*)d_in[2];
  const float* cam_trans = (const float*)d_in[3];
  const float* cam_intr  = (const float*)d_in[4];
  const float* pc_xyz    = (const float*)d_in[5];
  const float* scales    = (const float*)d_in[6];
  const float* rots      = (const float*)d_in[7];
  float* out = (float*)d_out;

  const int N    = in_sizes[5] / 3;       // 6144
  const int NCAM = in_sizes[4] / 4;       // B*NC = 6
  const int B    = in_sizes[1] / N;       // 1
  const int NC   = NCAM / B;              // 6

  unsigned char* ws = (unsigned char*)d_ws;
  int* counts = (int*)ws;
  int* order  = (int*)(ws + 256);
  size_t orderBytes = (size_t)NCAM * N * sizeof(int);
  size_t aosOff = (256 + orderBytes + 255) & ~(size_t)255;
  float* aos = (float*)(ws + aosOff);
  // ws needed: 256 + 147KB + 5.9MB ~= 6.1 MB

  sort_kernel<<<dim3(NCAM), 1024, 0, stream>>>(pc_xyz, cam_rot, cam_trans, N, counts, order);
  gather_kernel<<<dim3((N + 255) / 256, NCAM), 256, 0, stream>>>(
      vox, density, cam_rot, cam_trans, cam_intr, pc_xyz, scales, rots,
      counts, order, aos, N, NC);
  render_kernel<<<dim3((WW/16)*(HH/4), NCAM), 64, 0, stream>>>(aos, counts, out, N);
}

// Round 2
// 144.852 us; speedup vs baseline: 1.0320x; 1.0320x over previous
//
#include <hip/hip_runtime.h>

#define NEARV    0.2f
#define LOWPASSV 0.3f

constexpr int HH = 80, WW = 80;
constexpr int CFE = 32;          // feature channels
constexpr int GSTRIDE = 40;      // floats per gaussian record (8 hdr + 32 feat)
constexpr int RCHUNK = 32;       // gaussians staged per LDS chunk (render)
constexpr int MPAD = 8192;       // padded sort size (N=6144)

typedef unsigned long long u64;
typedef unsigned int u32;

__device__ __forceinline__ u64 shfl_xor64(u64 v, int m) {
  int lo = __shfl_xor((int)(v & 0xffffffffull), m);
  int hi = __shfl_xor((int)(v >> 32), m);
  return ((u64)(u32)hi << 32) | (u32)lo;
}

template <int J>
__device__ __forceinline__ void regpass(u64 (&key)[8], int g0, int k) {
  #pragma unroll
  for (int e = 0; e < 8; ++e) {
    if ((e & J) == 0) {
      bool up = (((g0 + e) & k) == 0);
      u64 a = key[e], b = key[e | J];
      bool sw = up ? (a > b) : (a < b);
      u64 hi = sw ? a : b;
      key[e]     = sw ? b : a;
      key[e | J] = hi;
    }
  }
}

// ---------------- Kernel A: per-camera stable depth sort ----------------
// Hybrid bitonic: 8 keys/thread in registers; j<8 in regs (no sync),
// 8<=j<=256 via shfl_xor (ds_bpermute, no barrier), j>=512 via LDS
// (10 passes x 2 barriers vs 91 barriers for pure-LDS bitonic).
// Key = (tz_bits<<32)|index reproduces JAX stable argsort exactly;
// invalid (z<=NEAR) keys = ~0 sort to the end.
__global__ __launch_bounds__(1024) void sort_kernel(
    const float* __restrict__ pc_xyz, const float* __restrict__ cam_rot,
    const float* __restrict__ cam_trans, int N,
    int* __restrict__ counts, int* __restrict__ order)
{
  __shared__ u64 smem[MPAD];     // 64 KB, swizzled slot = (e<<10)|(g>>3)
  __shared__ int scount;
  const int cam = blockIdx.x;
  const int tid = threadIdx.x;
  const int lane = tid & 63;
  const float R20 = cam_rot[cam*9+6], R21 = cam_rot[cam*9+7], R22 = cam_rot[cam*9+8];
  const float t2  = cam_trans[cam*3+2];
  if (tid == 0) scount = 0;
  __syncthreads();

  const int g0 = tid * 8;
  u64 key[8];
  int cnt = 0;
  #pragma unroll
  for (int e = 0; e < 8; ++e) {
    const int n = g0 + e;
    u64 kk = ~0ull;
    if (n < N) {
      float c2 = R20*pc_xyz[n*3+0] + R21*pc_xyz[n*3+1] + R22*pc_xyz[n*3+2] + t2;
      if (c2 > NEARV) { ++cnt; kk = ((u64)__float_as_uint(c2) << 32) | (u32)n; }
    }
    key[e] = kk;
  }
  // valid count: wave reduce + one shared atomic per wave
  int c = cnt;
  #pragma unroll
  for (int off = 32; off > 0; off >>= 1) c += __shfl_down(c, off);
  if (lane == 0) atomicAdd(&scount, c);

  for (int k = 2; k <= MPAD; k <<= 1) {
    for (int j = k >> 1; j >= 8; j >>= 1) {
      if (j >= 512) {
        __syncthreads();                       // protect prior reads
        #pragma unroll
        for (int e = 0; e < 8; ++e)
          smem[(e << 10) | ((g0 + e) >> 3)] = key[e];
        __syncthreads();
        #pragma unroll
        for (int e = 0; e < 8; ++e) {
          int g = g0 + e;
          u64 part = smem[(e << 10) | (((g ^ j)) >> 3)];
          bool up = ((g & k) == 0);
          bool lower = ((g & j) == 0);
          u64 mine = key[e];
          u64 mn = mine < part ? mine : part;
          u64 mx = mine < part ? part : mine;
          key[e] = (lower == up) ? mn : mx;
        }
      } else {
        int m = j >> 3;                        // lane xor distance (1..32)
        #pragma unroll
        for (int e = 0; e < 8; ++e) {
          int g = g0 + e;
          u64 mine = key[e];
          u64 part = shfl_xor64(mine, m);
          bool up = ((g & k) == 0);
          bool lower = ((g & j) == 0);
          u64 mn = mine < part ? mine : part;
          u64 mx = mine < part ? part : mine;
          key[e] = (lower == up) ? mn : mx;
        }
      }
    }
    if (k >= 8)      { regpass<4>(key, g0, k); regpass<2>(key, g0, k); regpass<1>(key, g0, k); }
    else if (k == 4) { regpass<2>(key, g0, k); regpass<1>(key, g0, k); }
    else             { regpass<1>(key, g0, k); }
  }

  __syncthreads();
  const int total = scount;
  if (g0 < total) {
    int t8[8];
    #pragma unroll
    for (int e = 0; e < 8; ++e) t8[e] = (int)(key[e] & 0xffffffffull);
    int* ob = order + (size_t)cam * N + g0;
    if (g0 + 8 <= total) {
      ((int4*)ob)[0] = make_int4(t8[0], t8[1], t8[2], t8[3]);
      ((int4*)ob)[1] = make_int4(t8[4], t8[5], t8[6], t8[7]);
    } else {
      for (int e = 0; e < total - g0; ++e) ob[e] = t8[e];
    }
  }
  if (tid == 0) counts[cam] = total;
}

// ---------------- Kernel B: project + pack sorted AoS ----------------
__global__ void gather_kernel(
    const float* __restrict__ vox, const float* __restrict__ density,
    const float* __restrict__ cam_rot, const float* __restrict__ cam_trans,
    const float* __restrict__ cam_intr, const float* __restrict__ pc_xyz,
    const float* __restrict__ scales, const float* __restrict__ rots,
    const int* __restrict__ counts, const int* __restrict__ order,
    float* __restrict__ aos, int N, int NC)
{
  const int cam = blockIdx.y;
  const int k = blockIdx.x * blockDim.x + threadIdx.x;
  if (k >= counts[cam]) return;
  const int n = order[(size_t)cam * N + k];
  const int b = cam / NC;
  const float* R = cam_rot + cam*9;
  const float* t = cam_trans + cam*3;
  const float* intr = cam_intr + cam*4;
  float p0 = pc_xyz[n*3+0], p1 = pc_xyz[n*3+1], p2 = pc_xyz[n*3+2];
  float c0 = R[0]*p0 + R[1]*p1 + R[2]*p2 + t[0];
  float c1 = R[3]*p0 + R[4]*p1 + R[5]*p2 + t[1];
  float c2 = R[6]*p0 + R[7]*p1 + R[8]*p2 + t[2];
  float tz = fmaxf(c2, 1e-6f);
  float itz = 1.0f / tz;
  float fx = intr[0], fy = intr[1], cx = intr[2], cy = intr[3];
  float u = fx*c0*itz + cx;
  float v = fy*c1*itz + cy;
  float j00 = fx*itz, j02 = -fx*c0*itz*itz;
  float j11 = fy*itz, j12 = -fy*c1*itz*itz;
  float A00 = j00*R[0] + j02*R[6];
  float A01 = j00*R[1] + j02*R[7];
  float A02 = j00*R[2] + j02*R[8];
  float A10 = j11*R[3] + j12*R[6];
  float A11 = j11*R[4] + j12*R[7];
  float A12 = j11*R[5] + j12*R[8];
  float qw = rots[n*4+0], qx = rots[n*4+1], qy = rots[n*4+2], qz = rots[n*4+3];
  float s = expf(scales[n]);
  float m00 = s*(1.f-2.f*(qy*qy+qz*qz)), m01 = s*(2.f*(qx*qy-qw*qz)), m02 = s*(2.f*(qx*qz+qw*qy));
  float m10 = s*(2.f*(qx*qy+qw*qz)), m11 = s*(1.f-2.f*(qx*qx+qz*qz)), m12 = s*(2.f*(qy*qz-qw*qx));
  float m20 = s*(2.f*(qx*qz-qw*qy)), m21 = s*(2.f*(qy*qz+qw*qx)), m22 = s*(1.f-2.f*(qx*qx+qy*qy));
  float B00 = A00*m00 + A01*m10 + A02*m20;
  float B01 = A00*m01 + A01*m11 + A02*m21;
  float B02 = A00*m02 + A01*m12 + A02*m22;
  float B10 = A10*m00 + A11*m10 + A12*m20;
  float B11 = A10*m01 + A11*m11 + A12*m21;
  float B12 = A10*m02 + A11*m12 + A12*m22;
  float cov00 = B00*B00 + B01*B01 + B02*B02;
  float cov01 = B00*B10 + B01*B11 + B02*B12;
  float cov11 = B10*B10 + B11*B11 + B12*B12;
  float a = cov00 + LOWPASSV, bb = cov01, cc = cov11 + LOWPASSV;
  float idet = 1.0f / (a*cc - bb*bb);
  float d = density[(size_t)b*N + n];
  float op = fmaxf(d, 0.f) + log1pf(expf(-fabsf(d)));   // stable softplus
  float* g = aos + ((size_t)cam*N + k) * GSTRIDE;
  g[0]=u; g[1]=v; g[2]=cc*idet; g[3]=-bb*idet; g[4]=a*idet; g[5]=op; g[6]=0.f; g[7]=0.f;
  const float4* f4 = (const float4*)(vox + ((size_t)b*N + n)*CFE);
  float4* o4 = (float4*)(g + 8);
  #pragma unroll
  for (int i = 0; i < CFE/4; ++i) o4[i] = f4[i];
}

// ---------------- Kernel C: per-tile front-to-back compositing ----------------
// One 64-lane wave per 16x4 tile. Per 32-gaussian chunk:
//   phase 1: unconditional alpha eval (32 independent chains, no divergence)
//   phase 2: T-prefix as 2 independent 16-long product chains (monoid combine)
//   phase 3: __any-guarded unconditional feature FMA (uniform branch)
__global__ __launch_bounds__(64) void render_kernel(
    const float* __restrict__ aos, const int* __restrict__ counts,
    float* __restrict__ out, int N)
{
  __shared__ float sg[RCHUNK * GSTRIDE];       // 5 KB
  const int cam = blockIdx.y;
  const int tile = blockIdx.x;                 // 5 x 20 tiles of 16x4 px
  const int tx = tile % (WW/16), ty = tile / (WW/16);
  const int lx = threadIdx.x & 15, ly = threadIdx.x >> 4;
  const int px = tx*16 + lx, py = ty*4 + ly;
  const float fpx = (float)px, fpy = (float)py;
  const int count = counts[cam];
  const float* aosCam = aos + (size_t)cam * N * GSTRIDE;

  float acc[CFE];
  #pragma unroll
  for (int i = 0; i < CFE; ++i) acc[i] = 0.f;
  float T = 1.0f;

  for (int k0 = 0; k0 < count; k0 += RCHUNK) {
    const int nks = min(RCHUNK, count - k0);
    if (nks < RCHUNK) {                        // zero-pad tail (op=0 -> alpha=0)
      for (int i = threadIdx.x; i < RCHUNK*GSTRIDE/4; i += 64)
        ((float4*)sg)[i] = make_float4(0.f,0.f,0.f,0.f);
      __syncthreads();
    }
    const float4* src = (const float4*)(aosCam + (size_t)k0 * GSTRIDE);
    for (int i = threadIdx.x; i < nks * (GSTRIDE/4); i += 64) ((float4*)sg)[i] = src[i];
    __syncthreads();

    // phase 1: alphas
    float al[RCHUNK];
    #pragma unroll
    for (int gi = 0; gi < RCHUNK; ++gi) {
      const float* gp = sg + gi * GSTRIDE;
      float4 h0 = *(const float4*)(gp);        // u, v, ia, ib
      float2 h1 = *(const float2*)(gp + 4);    // ic, op
      float dx = fpx - h0.x, dy = fpy - h0.y;
      float power = -0.5f*(h0.z*dx*dx + h1.x*dy*dy) - h0.w*dx*dy;
      float a = fminf(h1.y * __expf(fminf(power, 0.f)), 0.99f);
      al[gi] = (power > -16.f) ? a : 0.f;      // exp(-16)=1.1e-7: negligible
    }
    // phase 2: two independent prefix-product chains of 16
    float P0 = T, P1 = 1.f;
    #pragma unroll
    for (int i = 0; i < 16; ++i) {
      float a0 = al[i], a1 = al[16+i];
      al[i]    = a0 * P0;  P0 *= (1.f - a0);
      al[16+i] = a1 * P1;  P1 *= (1.f - a1);
    }
    #pragma unroll
    for (int i = 16; i < 32; ++i) al[i] *= P0; // monoid combine
    T = P0 * P1;
    // phase 3: feature accumulation
    #pragma unroll
    for (int gi = 0; gi < RCHUNK; ++gi) {
      float wv = al[gi];
      if (__any(wv > 1e-8f)) {
        const float4* f4 = (const float4*)(sg + gi*GSTRIDE + 8);
        #pragma unroll
        for (int c8 = 0; c8 < CFE/4; ++c8) {
          float4 fv = f4[c8];
          acc[c8*4+0] += wv*fv.x; acc[c8*4+1] += wv*fv.y;
          acc[c8*4+2] += wv*fv.z; acc[c8*4+3] += wv*fv.w;
        }
      }
    }
    __syncthreads();
    if (__all(T < 1e-4f)) break;               // all 64 px saturated
  }
  float* ob = out + (((size_t)cam * CFE) * HH + py) * WW + px;
  #pragma unroll
  for (int c = 0; c < CFE; ++c) ob[(size_t)c * HH * WW] = acc[c];
}

extern "C" void kernel_launch(void* const* d_in, const int* in_sizes, int n_in,
                              void* d_out, int out_size, void* d_ws, size_t ws_size,
                              hipStream_t stream) {
  const float* vox       = (const float*)d_in[0];
  const float* density   = (const float*)d_in[1];
  const float* cam_rot   = (const float*)d_in[2];
  const float* cam_trans = (const float*)d_in[3];
  const float* cam_intr  = (const float*)d_in[4];
  const float* pc_xyz    = (const float*)d_in[5];
  const float* scales    = (const float*)d_in[6];
  const float* rots      = (const float*)d_in[7];
  float* out = (float*)d_out;

  const int N    = in_sizes[5] / 3;       // 6144
  const int NCAM = in_sizes[4] / 4;       // B*NC = 6
  const int B    = in_sizes[1] / N;       // 1
  const int NC   = NCAM / B;              // 6

  unsigned char* ws = (unsigned char*)d_ws;
  int* countsPtr = (int*)ws;
  int* order  = (int*)(ws + 256);
  size_t orderBytes = (size_t)NCAM * N * sizeof(int);
  size_t aosOff = (256 + orderBytes + 255) & ~(size_t)255;
  float* aos = (float*)(ws + aosOff);

  sort_kernel<<<dim3(NCAM), 1024, 0, stream>>>(pc_xyz, cam_rot, cam_trans, N, countsPtr, order);
  gather_kernel<<<dim3((N + 255) / 256, NCAM), 256, 0, stream>>>(
      vox, density, cam_rot, cam_trans, cam_intr, pc_xyz, scales, rots,
      countsPtr, order, aos, N, NC);
  render_kernel<<<dim3((WW/16)*(HH/4), NCAM), 64, 0, stream>>>(aos, countsPtr, out, N);
}

// Round 3
// 103.497 us; speedup vs baseline: 1.4443x; 1.3996x over previous
//
#include <hip/hip_runtime.h>

#define NEARV    0.2f
#define LOWPASSV 0.3f

constexpr int HH = 80, WW = 80;
constexpr int CFE = 32;          // feature channels
constexpr int GSTRIDE = 40;      // floats per gaussian record (8 hdr + 32 feat)
constexpr int RCHUNK = 32;       // gaussians staged per LDS chunk (render)

constexpr int STHREADS = 1024;
constexpr int SWAVES = 16;
constexpr int SLOTS = 6;                       // elems per thread
constexpr int SCAP = STHREADS * SLOTS;         // 6144 = N

typedef unsigned long long u64;
typedef unsigned int u32;

// ---------------- Kernel A: per-camera stable radix argsort ----------------
// LSD radix, 4 passes x 8-bit digits on 32-bit depth bits (positive floats:
// uint order == float order). LSD radix is STABLE -> exactly reproduces JAX
// stable argsort tie-breaking with payload=index. Invalid (z<=NEAR) keys =
// 0xFFFFFFFF sort to the end and are never emitted.
// Element layout is slot-major (pos = wave*384 + slot*64 + lane) so ballot
// ranking order matches element order.
__global__ __launch_bounds__(1024) void sort_kernel(
    const float* __restrict__ pc_xyz, const float* __restrict__ cam_rot,
    const float* __restrict__ cam_trans, int N,
    int* __restrict__ counts, int* __restrict__ order)
{
  __shared__ u32 skey[SCAP];          // 24 KB
  __shared__ u32 spay[SCAP];          // 24 KB
  __shared__ u32 whist[SWAVES * 256]; // 16 KB
  __shared__ u32 binstart[256];
  __shared__ u32 wpart[4];
  __shared__ int scount;

  const int cam = blockIdx.x;
  const int tid = threadIdx.x;
  const int wv = tid >> 6, ln = tid & 63;
  const float R20 = cam_rot[cam*9+6], R21 = cam_rot[cam*9+7], R22 = cam_rot[cam*9+8];
  const float t2  = cam_trans[cam*3+2];
  if (tid == 0) scount = 0;
  __syncthreads();

  // init keys in original index order (coalesced)
  int cnt = 0;
  for (int i = tid; i < SCAP; i += STHREADS) {
    u32 kk = 0xFFFFFFFFu;
    if (i < N) {
      float c2 = R20*pc_xyz[i*3+0] + R21*pc_xyz[i*3+1] + R22*pc_xyz[i*3+2] + t2;
      if (c2 > NEARV) { kk = __float_as_uint(c2); ++cnt; }
    }
    skey[i] = kk; spay[i] = (u32)i;
  }
  int c = cnt;
  #pragma unroll
  for (int off = 32; off > 0; off >>= 1) c += __shfl_down(c, off);
  if (ln == 0) atomicAdd(&scount, c);

  const int base = wv * (SLOTS*64) + ln;
  u32* wh = whist + (wv << 8);

  for (int pass = 0; pass < 4; ++pass) {
    const int sh = pass * 8;
    for (int i = tid; i < SWAVES*256; i += STHREADS) whist[i] = 0;
    __syncthreads();

    u32 k[SLOTS], p[SLOTS], rnk[SLOTS];
    int dg[SLOTS];
    #pragma unroll
    for (int s = 0; s < SLOTS; ++s) { k[s] = skey[base + s*64]; p[s] = spay[base + s*64]; }

    // ballot ranking, slot-serial with running per-wave histogram (stability)
    #pragma unroll
    for (int s = 0; s < SLOTS; ++s) {
      int d = (int)((k[s] >> sh) & 255u);
      u64 m = ~0ull;
      #pragma unroll
      for (int b = 0; b < 8; ++b) {
        u64 bb = __ballot((d >> b) & 1);
        m &= ((d >> b) & 1) ? bb : ~bb;
      }
      u32 lower = (u32)__popcll(m & ((1ull << ln) - 1ull));
      u32 prev = wh[d];
      rnk[s] = prev + lower;
      dg[s] = d;
      if (lower == 0) wh[d] = prev + (u32)__popcll(m);   // one leader per digit: no race
      __builtin_amdgcn_wave_barrier();                   // keep slot order (wave lockstep)
    }
    __syncthreads();

    // per-digit exclusive scan over waves; digit totals -> binstart
    if (tid < 256) {
      u32 tot = 0;
      #pragma unroll
      for (int w = 0; w < SWAVES; ++w) {
        u32 t = whist[(w << 8) + tid];
        whist[(w << 8) + tid] = tot;
        tot += t;
      }
      binstart[tid] = tot;
    }
    __syncthreads();
    // exclusive scan of 256 digit totals (4 waves: shfl scan + partial combine)
    u32 v = 0, inc = 0;
    if (tid < 256) {
      v = binstart[tid]; inc = v;
      #pragma unroll
      for (int off = 1; off < 64; off <<= 1) {
        u32 t = __shfl_up(inc, off);
        if (ln >= off) inc += t;
      }
      if (ln == 63) wpart[tid >> 6] = inc;
    }
    __syncthreads();
    if (tid < 256) {
      u32 add = 0;
      for (int i = 0; i < (tid >> 6); ++i) add += wpart[i];
      binstart[tid] = add + inc - v;
    }
    __syncthreads();

    // scatter (all reads of skey/spay done before the scan barriers)
    #pragma unroll
    for (int s = 0; s < SLOTS; ++s) {
      u32 pos = binstart[dg[s]] + wh[dg[s]] + rnk[s];
      skey[pos] = k[s]; spay[pos] = p[s];
    }
    __syncthreads();
  }

  const int total = scount;
  for (int i = tid; i < total; i += STHREADS)
    order[(size_t)cam * N + i] = (int)spay[i];
  if (tid == 0) counts[cam] = total;
}

// ---------------- Kernel B: project + pack sorted AoS ----------------
__global__ void gather_kernel(
    const float* __restrict__ vox, const float* __restrict__ density,
    const float* __restrict__ cam_rot, const float* __restrict__ cam_trans,
    const float* __restrict__ cam_intr, const float* __restrict__ pc_xyz,
    const float* __restrict__ scales, const float* __restrict__ rots,
    const int* __restrict__ counts, const int* __restrict__ order,
    float* __restrict__ aos, int N, int NC)
{
  const int cam = blockIdx.y;
  const int k = blockIdx.x * blockDim.x + threadIdx.x;
  if (k >= counts[cam]) return;
  const int n = order[(size_t)cam * N + k];
  const int b = cam / NC;
  const float* R = cam_rot + cam*9;
  const float* t = cam_trans + cam*3;
  const float* intr = cam_intr + cam*4;
  float p0 = pc_xyz[n*3+0], p1 = pc_xyz[n*3+1], p2 = pc_xyz[n*3+2];
  float c0 = R[0]*p0 + R[1]*p1 + R[2]*p2 + t[0];
  float c1 = R[3]*p0 + R[4]*p1 + R[5]*p2 + t[1];
  float c2 = R[6]*p0 + R[7]*p1 + R[8]*p2 + t[2];
  float tz = fmaxf(c2, 1e-6f);
  float itz = 1.0f / tz;
  float fx = intr[0], fy = intr[1], cx = intr[2], cy = intr[3];
  float u = fx*c0*itz + cx;
  float v = fy*c1*itz + cy;
  float j00 = fx*itz, j02 = -fx*c0*itz*itz;
  float j11 = fy*itz, j12 = -fy*c1*itz*itz;
  float A00 = j00*R[0] + j02*R[6];
  float A01 = j00*R[1] + j02*R[7];
  float A02 = j00*R[2] + j02*R[8];
  float A10 = j11*R[3] + j12*R[6];
  float A11 = j11*R[4] + j12*R[7];
  float A12 = j11*R[5] + j12*R[8];
  float qw = rots[n*4+0], qx = rots[n*4+1], qy = rots[n*4+2], qz = rots[n*4+3];
  float s = expf(scales[n]);
  float m00 = s*(1.f-2.f*(qy*qy+qz*qz)), m01 = s*(2.f*(qx*qy-qw*qz)), m02 = s*(2.f*(qx*qz+qw*qy));
  float m10 = s*(2.f*(qx*qy+qw*qz)), m11 = s*(1.f-2.f*(qx*qx+qz*qz)), m12 = s*(2.f*(qy*qz-qw*qx));
  float m20 = s*(2.f*(qx*qz-qw*qy)), m21 = s*(2.f*(qy*qz+qw*qx)), m22 = s*(1.f-2.f*(qx*qx+qy*qy));
  float B00 = A00*m00 + A01*m10 + A02*m20;
  float B01 = A00*m01 + A01*m11 + A02*m21;
  float B02 = A00*m02 + A01*m12 + A02*m22;
  float B10 = A10*m00 + A11*m10 + A12*m20;
  float B11 = A10*m01 + A11*m11 + A12*m21;
  float B12 = A10*m02 + A11*m12 + A12*m22;
  float cov00 = B00*B00 + B01*B01 + B02*B02;
  float cov01 = B00*B10 + B01*B11 + B02*B12;
  float cov11 = B10*B10 + B11*B11 + B12*B12;
  float a = cov00 + LOWPASSV, bb = cov01, cc = cov11 + LOWPASSV;
  float idet = 1.0f / (a*cc - bb*bb);
  float d = density[(size_t)b*N + n];
  float op = fmaxf(d, 0.f) + log1pf(expf(-fabsf(d)));   // stable softplus
  float* g = aos + ((size_t)cam*N + k) * GSTRIDE;
  g[0]=u; g[1]=v; g[2]=cc*idet; g[3]=-bb*idet; g[4]=a*idet; g[5]=op; g[6]=0.f; g[7]=0.f;
  const float4* f4 = (const float4*)(vox + ((size_t)b*N + n)*CFE);
  float4* o4 = (float4*)(g + 8);
  #pragma unroll
  for (int i = 0; i < CFE/4; ++i) o4[i] = f4[i];
}

// ---------------- Kernel C: per-tile front-to-back compositing ----------------
__global__ __launch_bounds__(64) void render_kernel(
    const float* __restrict__ aos, const int* __restrict__ counts,
    float* __restrict__ out, int N)
{
  __shared__ float sg[RCHUNK * GSTRIDE];       // 5 KB
  const int cam = blockIdx.y;
  const int tile = blockIdx.x;                 // 5 x 20 tiles of 16x4 px
  const int tx = tile % (WW/16), ty = tile / (WW/16);
  const int lx = threadIdx.x & 15, ly = threadIdx.x >> 4;
  const int px = tx*16 + lx, py = ty*4 + ly;
  const float fpx = (float)px, fpy = (float)py;
  const int count = counts[cam];
  const float* aosCam = aos + (size_t)cam * N * GSTRIDE;

  float acc[CFE];
  #pragma unroll
  for (int i = 0; i < CFE; ++i) acc[i] = 0.f;
  float T = 1.0f;

  for (int k0 = 0; k0 < count; k0 += RCHUNK) {
    const int nks = min(RCHUNK, count - k0);
    if (nks < RCHUNK) {                        // zero-pad tail (op=0 -> alpha=0)
      for (int i = threadIdx.x; i < RCHUNK*GSTRIDE/4; i += 64)
        ((float4*)sg)[i] = make_float4(0.f,0.f,0.f,0.f);
      __syncthreads();
    }
    const float4* src = (const float4*)(aosCam + (size_t)k0 * GSTRIDE);
    for (int i = threadIdx.x; i < nks * (GSTRIDE/4); i += 64) ((float4*)sg)[i] = src[i];
    __syncthreads();

    float al[RCHUNK];
    #pragma unroll
    for (int gi = 0; gi < RCHUNK; ++gi) {
      const float* gp = sg + gi * GSTRIDE;
      float4 h0 = *(const float4*)(gp);        // u, v, ia, ib
      float2 h1 = *(const float2*)(gp + 4);    // ic, op
      float dx = fpx - h0.x, dy = fpy - h0.y;
      float power = -0.5f*(h0.z*dx*dx + h1.x*dy*dy) - h0.w*dx*dy;
      float a = fminf(h1.y * __expf(fminf(power, 0.f)), 0.99f);
      al[gi] = (power > -16.f) ? a : 0.f;      // exp(-16)=1.1e-7: negligible
    }
    float P0 = T, P1 = 1.f;
    #pragma unroll
    for (int i = 0; i < 16; ++i) {
      float a0 = al[i], a1 = al[16+i];
      al[i]    = a0 * P0;  P0 *= (1.f - a0);
      al[16+i] = a1 * P1;  P1 *= (1.f - a1);
    }
    #pragma unroll
    for (int i = 16; i < 32; ++i) al[i] *= P0;
    T = P0 * P1;
    #pragma unroll
    for (int gi = 0; gi < RCHUNK; ++gi) {
      float wv = al[gi];
      if (__any(wv > 1e-8f)) {
        const float4* f4 = (const float4*)(sg + gi*GSTRIDE + 8);
        #pragma unroll
        for (int c8 = 0; c8 < CFE/4; ++c8) {
          float4 fv = f4[c8];
          acc[c8*4+0] += wv*fv.x; acc[c8*4+1] += wv*fv.y;
          acc[c8*4+2] += wv*fv.z; acc[c8*4+3] += wv*fv.w;
        }
      }
    }
    __syncthreads();
    if (__all(T < 1e-4f)) break;               // all 64 px saturated
  }
  float* ob = out + (((size_t)cam * CFE) * HH + py) * WW + px;
  #pragma unroll
  for (int c = 0; c < CFE; ++c) ob[(size_t)c * HH * WW] = acc[c];
}

extern "C" void kernel_launch(void* const* d_in, const int* in_sizes, int n_in,
                              void* d_out, int out_size, void* d_ws, size_t ws_size,
                              hipStream_t stream) {
  const float* vox       = (const float*)d_in[0];
  const float* density   = (const float*)d_in[1];
  const float* cam_rot   = (const float*)d_in[2];
  const float* cam_trans = (const float*)d_in[3];
  const float* cam_intr  = (const float*)d_in[4];
  const float* pc_xyz    = (const float*)d_in[5];
  const float* scales    = (const float*)d_in[6];
  const float* rots      = (const float*)d_in[7];
  float* out = (float*)d_out;

  const int N    = in_sizes[5] / 3;       // 6144
  const int NCAM = in_sizes[4] / 4;       // B*NC = 6
  const int B    = in_sizes[1] / N;       // 1
  const int NC   = NCAM / B;              // 6

  unsigned char* ws = (unsigned char*)d_ws;
  int* countsPtr = (int*)ws;
  int* order  = (int*)(ws + 256);
  size_t orderBytes = (size_t)NCAM * N * sizeof(int);
  size_t aosOff = (256 + orderBytes + 255) & ~(size_t)255;
  float* aos = (float*)(ws + aosOff);

  sort_kernel<<<dim3(NCAM), STHREADS, 0, stream>>>(pc_xyz, cam_rot, cam_trans, N, countsPtr, order);
  gather_kernel<<<dim3((N + 255) / 256, NCAM), 256, 0, stream>>>(
      vox, density, cam_rot, cam_trans, cam_intr, pc_xyz, scales, rots,
      countsPtr, order, aos, N, NC);
  render_kernel<<<dim3((WW/16)*(HH/4), NCAM), 64, 0, stream>>>(aos, countsPtr, out, N);
}